// Round 4
// baseline (884.208 us; speedup 1.0000x reference)
//
#include <hip/hip_runtime.h>
#include <hip/hip_bf16.h>
#include <hip/hip_fp16.h>
#include <stdint.h>

#define N_NODES 100000
#define N_EDGES 1600000
#define IN_DIM 256
#define HID 128
#define N_LAYERS 4
#define OUT_DIM 7
#define LN_EPS 1e-5f

// counting-sort CSR build
#define BSHIFT 6
#define BROWS 64
#define NBK 1563                  // ceil(100000/64) buckets of 64 rows
#define CHUNK 16384               // edges per sort block
#define NCH ((N_EDGES + CHUNK - 1) / CHUNK)   // 98 (must be <= 128 for k_hscan)

typedef __attribute__((ext_vector_type(8))) short bf16x8;
typedef __attribute__((ext_vector_type(4))) float f32x4;

__device__ inline float bf2f1(uint16_t u) {
    union { uint32_t i; float f; } a; a.i = ((uint32_t)u) << 16; return a.f;
}
__device__ inline uint16_t f2bf(float f) {
    union { float f; uint32_t i; } a; a.f = f;
    uint32_t lsb = (a.i >> 16) & 1u;
    a.i += 0x7fffu + lsb;          // round-to-nearest-even
    return (uint16_t)(a.i >> 16);
}
__device__ inline uint32_t packq(float a, float b, float qinv) {
    int qa = __float2int_rn(a * qinv);
    int qb = __float2int_rn(b * qinv);
    return ((uint32_t)(uint16_t)(short)qa) | (((uint32_t)(uint16_t)(short)qb) << 16);
}

// ---------------- dtype detection ----------------
__global__ void k_detect(const uint32_t* __restrict__ W, int* __restrict__ flag) {
    if (threadIdx.x == 0 && blockIdx.x == 0) {
        int cnt = 0;
        for (int i = 0; i < 64; i++) {
            uint32_t lo = W[i] & 0xffffu;
            uint32_t ex = (lo >> 7) & 0xff;
            if (ex >= 0x60 && ex < 0x7c) cnt++;
        }
        *flag = (cnt < 32) ? 1 : 0;   // 1 = fp32 inputs, 0 = bf16 inputs
    }
}

// ---------------- weight canonicalization (all weights -> fp32 staged) ----------------
__global__ __launch_bounds__(256) void k_cvt(const void* a0, const void* a1, const void* a2,
                                             const void* a3, const void* a4, const void* a5,
                                             const void* a6, const void* a7, const void* a8,
                                             float* __restrict__ dst, const int* __restrict__ flag) {
    int t = blockIdx.x * 256 + threadIdx.x;
    if (t >= 99720) return;
    const void* src; int i; int off;
    if      (t < 32768) { src = a0; i = t;         off = 0;     }   // W_proj 256x128
    else if (t < 32896) { src = a1; i = t - 32768; off = 32768; }   // b_proj 128
    else if (t < 33024) { src = a2; i = t - 32896; off = 32896; }   // gamma 128
    else if (t < 33152) { src = a3; i = t - 33024; off = 33024; }   // beta 128
    else if (t < 33280) { src = a4; i = t - 33152; off = 33152; }   // q_w 128
    else if (t < 33281) { src = a5; i = t - 33280; off = 33280; }   // q_b 1
    else if (t < 98817) { src = a6; i = t - 33281; off = 33296; }   // conv_w 4x128x128
    else if (t < 99713) { src = a7; i = t - 98817; off = 98832; }   // cls_w 128x7
    else                { src = a8; i = t - 99713; off = 99728; }   // cls_b 7
    float v;
    if (*flag) v = ((const float*)src)[i];
    else       v = bf2f1(((const uint16_t*)src)[i]);
    dst[off + i] = v;
}

// ---------------- split-bf16 transposed weight prep ----------------
__global__ __launch_bounds__(256) void k_wsplit(const float* __restrict__ stg,
                                                uint16_t* __restrict__ wpThi, uint16_t* __restrict__ wpTlo,
                                                uint16_t* __restrict__ cwThi, uint16_t* __restrict__ cwTlo) {
    int t = blockIdx.x * 256 + threadIdx.x;
    if (t >= 32768 + 65536) return;
    float v; size_t dst; uint16_t *ha, *la;
    if (t < 32768) {
        int k = t >> 7, c = t & 127;
        v = stg[t];
        dst = (size_t)c * 256 + k; ha = wpThi; la = wpTlo;
    } else {
        int u = t - 32768;
        int L = u >> 14, rem = u & 16383;
        int k = rem >> 7, c = rem & 127;
        v = stg[33296 + u];
        dst = (size_t)L * 16384 + (size_t)c * 128 + k; ha = cwThi; la = cwTlo;
    }
    uint16_t hb = f2bf(v);
    uint16_t lb = f2bf(v - bf2f1(hb));
    ha[dst] = hb; la[dst] = lb;
}

// ---------------- graph prep: atomic-free counting-sort CSR build ----------------

__global__ __launch_bounds__(256) void k_hist(const int* __restrict__ row, int* __restrict__ hist) {
    __shared__ int lh[NBK];
    int b = blockIdx.x, tid = threadIdx.x;
    for (int i = tid; i < NBK; i += 256) lh[i] = 0;
    __syncthreads();
    int e0 = b * CHUNK;
    int lim = N_EDGES - e0; if (lim > CHUNK) lim = CHUNK;
    for (int i = tid; i < lim; i += 256) atomicAdd(&lh[row[e0 + i] >> BSHIFT], 1);
    __syncthreads();
    for (int i = tid; i < NBK; i += 256) hist[(size_t)b * NBK + i] = lh[i];
}

__global__ __launch_bounds__(128) void k_hscan(int* __restrict__ hist, int* __restrict__ totB) {
    __shared__ int s[128];
    int bkt = blockIdx.x, t = threadIdx.x;
    int v = (t < NCH) ? hist[(size_t)t * NBK + bkt] : 0;
    s[t] = v;
    __syncthreads();
    for (int off = 1; off < 128; off <<= 1) {
        int add = (t >= off) ? s[t - off] : 0;
        __syncthreads();
        s[t] += add;
        __syncthreads();
    }
    if (t < NCH) hist[(size_t)t * NBK + bkt] = s[t] - v;   // exclusive within bucket
    if (t == 127) totB[bkt] = s[127];
}

__global__ __launch_bounds__(256) void k_bscan(const int* __restrict__ totB,
                                               int* __restrict__ boffB, int* __restrict__ rp) {
    __shared__ int ps[256];
    int t = threadIdx.x;
    const int STRIP = 7;                     // 256*7 = 1792 >= NBK
    int base = t * STRIP;
    int loc[STRIP]; int sum = 0;
#pragma unroll
    for (int j = 0; j < STRIP; j++) {
        int idx = base + j;
        int v = (idx < NBK) ? totB[idx] : 0;
        loc[j] = sum; sum += v;
    }
    ps[t] = sum;
    __syncthreads();
    int v = ps[t];
    for (int off = 1; off < 256; off <<= 1) {
        int add = (t >= off) ? ps[t - off] : 0;
        __syncthreads();
        ps[t] += add;
        __syncthreads();
    }
    int excl = ps[t] - v;
#pragma unroll
    for (int j = 0; j < STRIP; j++) {
        int idx = base + j;
        if (idx < NBK) boffB[idx] = excl + loc[j];
    }
    if (t == 0) { boffB[NBK] = N_EDGES; rp[N_NODES] = N_EDGES; }
}

__global__ __launch_bounds__(256) void k_sortscat(const int* __restrict__ row, const int* __restrict__ col,
                                                  const int* __restrict__ hist, const int* __restrict__ boffB,
                                                  uint32_t* __restrict__ ebp) {
    __shared__ int dbase[NBK];
    __shared__ int lcnt[NBK];
    int b = blockIdx.x, tid = threadIdx.x;
    for (int i = tid; i < NBK; i += 256) {
        dbase[i] = boffB[i] + hist[(size_t)b * NBK + i];
        lcnt[i] = 0;
    }
    __syncthreads();
    int e0 = b * CHUNK;
    int lim = N_EDGES - e0; if (lim > CHUNK) lim = CHUNK;
    for (int i = tid; i < lim; i += 256) {
        int r = row[e0 + i], c = col[e0 + i];
        int bk = r >> BSHIFT;
        int rank = atomicAdd(&lcnt[bk], 1);
        ebp[dbase[bk] + rank] = ((uint32_t)(r & (BROWS - 1)) << 17) | (uint32_t)c;
    }
}

__global__ __launch_bounds__(256) void k_bfin(const uint32_t* __restrict__ ebp, const int* __restrict__ boffB,
                                              int* __restrict__ rp, float* __restrict__ dis,
                                              int* __restrict__ edc) {
    __shared__ int ldeg[BROWS];
    __shared__ int lcur[BROWS];
    int b = blockIdx.x, tid = threadIdx.x;
    int base = boffB[b];
    int n = boffB[b + 1] - base;
    if (tid < BROWS) ldeg[tid] = 0;
    __syncthreads();
    for (int i = tid; i < n; i += 256) atomicAdd(&ldeg[ebp[base + i] >> 17], 1);
    __syncthreads();
    if (tid == 0) {
        int run = 0;
        for (int r = 0; r < BROWS; r++) { int d = ldeg[r]; lcur[r] = run; run += d; }
    }
    __syncthreads();
    int row0 = b << BSHIFT;
    if (tid < BROWS && row0 + tid < N_NODES) {
        int d = ldeg[tid];
        rp[row0 + tid]  = base + lcur[tid];
        dis[row0 + tid] = rsqrtf((float)(d > 0 ? d : 1));
    }
    __syncthreads();   // rp/dis read lcur before scatter mutates it
    for (int i = tid; i < n; i += 256) {
        uint32_t pk = ebp[base + i];
        int r = pk >> 17;
        int pos = atomicAdd(&lcur[r], 1);
        edc[base + pos] = (int)(pk & 0x1FFFFu);
    }
}

// ---------------- fused SpMM + blend ----------------
// one wave per node; lane holds cols {lane, lane+64}; 8-deep gather unroll.

__global__ __launch_bounds__(256) void k_spmm(const uint32_t* __restrict__ Hq,
                                              const float* __restrict__ ScD,
                                              const float* __restrict__ H0,
                                              const int* __restrict__ rp,
                                              const int* __restrict__ edc,
                                              const float* __restrict__ S,
                                              const float* __restrict__ dis,
                                              float* __restrict__ Sup) {
    int wid  = (blockIdx.x * 256 + threadIdx.x) >> 6;
    int lane = threadIdx.x & 63;
    if (wid >= N_NODES) return;

    // hoist independent loads ahead of the gather loop
    float s  = S[wid];
    float dr = dis[wid];
    float h0x = H0[(size_t)wid * 128 + lane];
    float h0y = H0[(size_t)wid * 128 + 64 + lane];

    int p0 = rp[wid], p1 = rp[wid + 1];
    float ax = 0.f, ay = 0.f;
    int p = p0;
    for (; p + 8 <= p1; p += 8) {
        int c[8]; uint32_t u[8]; float w[8];
#pragma unroll
        for (int j = 0; j < 8; j++) c[j] = edc[p + j];
#pragma unroll
        for (int j = 0; j < 8; j++) u[j] = Hq[(size_t)c[j] * 64 + lane];
#pragma unroll
        for (int j = 0; j < 8; j++) w[j] = ScD[c[j]];
#pragma unroll
        for (int j = 0; j < 8; j++) {
            ax += w[j] * (float)((int)(u[j] << 16) >> 16);
            ay += w[j] * (float)((int)u[j] >> 16);
        }
    }
    for (; p + 4 <= p1; p += 4) {
        int c[4]; uint32_t u[4]; float w[4];
#pragma unroll
        for (int j = 0; j < 4; j++) c[j] = edc[p + j];
#pragma unroll
        for (int j = 0; j < 4; j++) u[j] = Hq[(size_t)c[j] * 64 + lane];
#pragma unroll
        for (int j = 0; j < 4; j++) w[j] = ScD[c[j]];
#pragma unroll
        for (int j = 0; j < 4; j++) {
            ax += w[j] * (float)((int)(u[j] << 16) >> 16);
            ay += w[j] * (float)((int)u[j] >> 16);
        }
    }
    for (; p < p1; p++) {
        int c = edc[p];
        uint32_t u = Hq[(size_t)c * 64 + lane];
        float w = ScD[c];
        ax += w * (float)((int)(u << 16) >> 16);
        ay += w * (float)((int)u >> 16);
    }
    float f = (1.f - s) * dr;
    Sup[(size_t)wid * 128 + lane]      = f * ax + s * h0x;
    Sup[(size_t)wid * 128 + 64 + lane] = f * ay + s * h0y;
}

// ---------------- split-bf16 MFMA GEMM + fused LN + gate + quant ----------------
// Block = 64 rows x 128 cols, 256 threads = 4 waves; wave w owns rows [w*16, w*16+16).
// C layout: col = lane&15, row = (lane>>4)*4 + reg.
// WF (weights-were-fp32) is a compile-time param selected by device-side dispatch:
//   WF=0 (bf16 inputs): Wlo==0 and (MODE0) Alo==0 exactly -> those planes/MFMAs dropped
//   WF=1: full 3-product split C = Ah*Wh + Ah*Wl + Al*Wh.
// Staging is register-double-buffered: chunk k+1's global loads issue under chunk k's MFMA.
// LDS tiles XOR-swizzled (byte ^= (row&7)<<4), identically on write and read.
// NOTE: Hout may alias Araw for MODE 1 (each row read/written only by its own lanes).

template <int KD, int MODE, int WH, int WQ, int WF>
__device__ __forceinline__ void gemm_body(
    const void* __restrict__ Araw, const uint16_t* __restrict__ WThi,
    const uint16_t* __restrict__ WTlo, const float* __restrict__ bias,
    const float* __restrict__ gamma, const float* __restrict__ beta,
    const float* __restrict__ qw, const float* __restrict__ qb, float theta,
    const float* __restrict__ dis, float* __restrict__ Hout,
    uint32_t* __restrict__ Hq, float* __restrict__ Sc, float* __restrict__ S,
    uint16_t* sAhi, uint16_t* sAlo, uint16_t* sBhi, uint16_t* sBlo)
{
    constexpr int F32A = (MODE == 0) ? WF : 1;   // A has a lo plane
    constexpr int NC = KD / 64;

    const int tid  = threadIdx.x;
    const int lane = tid & 63;
    const int wv   = tid >> 6;
    const int li   = lane & 15;
    const int lg   = lane >> 4;
    const size_t row0 = (size_t)blockIdx.x * 64;

    f32x4 acc[8];
#pragma unroll
    for (int ct = 0; ct < 8; ct++) acc[ct] = (f32x4){0.f, 0.f, 0.f, 0.f};

    // staging registers (double-buffer depth 1)
    float far[2][8];     // A fp32 path
    uint4 abr[2];        // A bf16 path
    uint4 bhr[4], blr[4];

    auto loadA = [&](int kc) {
#pragma unroll
        for (int it = 0; it < 2; it++) {
            int s = tid + it * 256;
            int r = s >> 3, sl = s & 7;
            size_t rg = row0 + r; if (rg >= N_NODES) rg = N_NODES - 1;
            if constexpr (F32A) {
                const float* p = (const float*)Araw + rg * KD + kc * 64 + sl * 8;
                float4 u0 = *(const float4*)p;
                float4 u1 = *(const float4*)(p + 4);
                far[it][0] = u0.x; far[it][1] = u0.y; far[it][2] = u0.z; far[it][3] = u0.w;
                far[it][4] = u1.x; far[it][5] = u1.y; far[it][6] = u1.z; far[it][7] = u1.w;
            } else {
                abr[it] = *(const uint4*)((const uint16_t*)Araw + rg * KD + kc * 64 + sl * 8);
            }
        }
    };
    auto storeA = [&]() {
#pragma unroll
        for (int it = 0; it < 2; it++) {
            int s = tid + it * 256;
            int r = s >> 3, sl = s & 7;
            uint32_t byte = (uint32_t)(r * 128 + sl * 16) ^ (uint32_t)((r & 7) << 4);
            if constexpr (F32A) {
                uint32_t hw[8], lw[8];
#pragma unroll
                for (int j = 0; j < 8; j++) {
                    uint16_t hb = f2bf(far[it][j]);
                    uint16_t lb = f2bf(far[it][j] - bf2f1(hb));
                    hw[j] = hb; lw[j] = lb;
                }
                uint4 vh, vl;
                vh.x = hw[0] | (hw[1] << 16); vh.y = hw[2] | (hw[3] << 16);
                vh.z = hw[4] | (hw[5] << 16); vh.w = hw[6] | (hw[7] << 16);
                vl.x = lw[0] | (lw[1] << 16); vl.y = lw[2] | (lw[3] << 16);
                vl.z = lw[4] | (lw[5] << 16); vl.w = lw[6] | (lw[7] << 16);
                *(uint4*)((char*)sAhi + byte) = vh;
                *(uint4*)((char*)sAlo + byte) = vl;
            } else {
                *(uint4*)((char*)sAhi + byte) = abr[it];
            }
        }
    };
    auto loadB = [&](int kc) {
#pragma unroll
        for (int it = 0; it < 4; it++) {
            int s = tid + it * 256;
            int r = s >> 3, sl = s & 7;
            size_t gsrc = (size_t)r * KD + kc * 64 + sl * 8;
            bhr[it] = *(const uint4*)(WThi + gsrc);
            if constexpr (WF) blr[it] = *(const uint4*)(WTlo + gsrc);
        }
    };
    auto storeB = [&]() {
#pragma unroll
        for (int it = 0; it < 4; it++) {
            int s = tid + it * 256;
            int r = s >> 3, sl = s & 7;
            uint32_t byte = (uint32_t)(r * 128 + sl * 16) ^ (uint32_t)((r & 7) << 4);
            *(uint4*)((char*)sBhi + byte) = bhr[it];
            if constexpr (WF) *(uint4*)((char*)sBlo + byte) = blr[it];
        }
    };

    loadA(0); loadB(0);
    for (int kc = 0; kc < NC; kc++) {
        storeA(); storeB();
        __syncthreads();
        if (kc + 1 < NC) { loadA(kc + 1); loadB(kc + 1); }   // fly under MFMA
#pragma unroll
        for (int ks = 0; ks < 2; ks++) {
            int arow = wv * 16 + li;
            uint32_t ab = (uint32_t)(arow * 128 + ks * 64 + lg * 16) ^ (uint32_t)((arow & 7) << 4);
            bf16x8 ah = *(const bf16x8*)((const char*)sAhi + ab);
            bf16x8 al;
            if constexpr (F32A) al = *(const bf16x8*)((const char*)sAlo + ab);
#pragma unroll
            for (int ct = 0; ct < 8; ct++) {
                int brow = ct * 16 + li;
                uint32_t bb = (uint32_t)(brow * 128 + ks * 64 + lg * 16) ^ (uint32_t)((brow & 7) << 4);
                bf16x8 bh = *(const bf16x8*)((const char*)sBhi + bb);
                acc[ct] = __builtin_amdgcn_mfma_f32_16x16x32_bf16(ah, bh, acc[ct], 0, 0, 0);
                if constexpr (F32A)
                    acc[ct] = __builtin_amdgcn_mfma_f32_16x16x32_bf16(al, bh, acc[ct], 0, 0, 0);
                if constexpr (WF) {
                    bf16x8 bl = *(const bf16x8*)((const char*)sBlo + bb);
                    acc[ct] = __builtin_amdgcn_mfma_f32_16x16x32_bf16(ah, bl, acc[ct], 0, 0, 0);
                }
            }
        }
        __syncthreads();
    }

    // ---- epilogue ----
    float gm[8], bt[8], qv[8], bi[8];
#pragma unroll
    for (int ct = 0; ct < 8; ct++) {
        int c = ct * 16 + li;
        gm[ct] = gamma[c]; bt[ct] = beta[c]; qv[ct] = qw[c];
        bi[ct] = (MODE == 0) ? bias[c] : 0.f;
    }
    const float qbv = qb[0];
    const float om  = 1.f - theta;
    const float* Af = (const float*)Araw;

#pragma unroll
    for (int r = 0; r < 4; r++) {
        int rowl  = wv * 16 + lg * 4 + r;
        size_t rg = row0 + rowl;
        size_t rc = (rg < N_NODES) ? rg : (N_NODES - 1);
        float v[8];
        if (MODE == 0) {
#pragma unroll
            for (int ct = 0; ct < 8; ct++) v[ct] = acc[ct][r] + bi[ct];
        } else {
#pragma unroll
            for (int ct = 0; ct < 8; ct++) {
                float sv = Af[rc * KD + ct * 16 + li];   // support re-read (L2-hot)
                float o  = theta * acc[ct][r] + om * sv;
                v[ct] = o > 0.f ? o : 0.f;
            }
        }
        float sum = 0.f, sq = 0.f;
#pragma unroll
        for (int ct = 0; ct < 8; ct++) { sum += v[ct]; sq += v[ct] * v[ct]; }
        sum += __shfl_xor(sum, 1); sum += __shfl_xor(sum, 2);
        sum += __shfl_xor(sum, 4); sum += __shfl_xor(sum, 8);
        sq  += __shfl_xor(sq, 1);  sq  += __shfl_xor(sq, 2);
        sq  += __shfl_xor(sq, 4);  sq  += __shfl_xor(sq, 8);
        float mu  = sum * (1.f / 128.f);
        float var = fmaxf(sq * (1.f / 128.f) - mu * mu, 0.f);
        float rs  = rsqrtf(var + LN_EPS);
        float y[8];
#pragma unroll
        for (int ct = 0; ct < 8; ct++) y[ct] = gm[ct] * (v[ct] - mu) * rs + bt[ct];

        if (WQ) {
            float zd = 0.f, am = 0.f;
#pragma unroll
            for (int ct = 0; ct < 8; ct++) { zd += y[ct] * qv[ct]; am = fmaxf(am, fabsf(y[ct])); }
            zd += __shfl_xor(zd, 1); zd += __shfl_xor(zd, 2);
            zd += __shfl_xor(zd, 4); zd += __shfl_xor(zd, 8);
            am = fmaxf(am, __shfl_xor(am, 1)); am = fmaxf(am, __shfl_xor(am, 2));
            am = fmaxf(am, __shfl_xor(am, 4)); am = fmaxf(am, __shfl_xor(am, 8));
            float amc  = fmaxf(am, 1e-20f);
            float qinv = 32767.f / amc;
            if (rg < N_NODES) {
                uint32_t* mq = Hq + rg * 64;
#pragma unroll
                for (int ct = 0; ct < 4; ct++)
                    mq[ct * 16 + li] = packq(y[ct], y[ct + 4], qinv);  // pair (c, c+64)
                if (li == 0) {
                    Sc[rg] = amc * (1.f / 32767.f) * dis[rg];   // fold dis[col] into scale
                    S[rg]  = 1.f / (1.f + __expf(-(zd + qbv - 1.f)));
                }
            }
        }
        if (WH && rg < N_NODES) {
            float* dst = Hout + rg * 128;
#pragma unroll
            for (int ct = 0; ct < 8; ct++) dst[ct * 16 + li] = y[ct];
        }
    }
}

template <int KD, int MODE, int WH, int WQ>
__global__ __launch_bounds__(256) void k_gemm_mfma(
    const void* __restrict__ Araw, const uint16_t* __restrict__ WThi,
    const uint16_t* __restrict__ WTlo, const float* __restrict__ bias,
    const float* __restrict__ gamma, const float* __restrict__ beta,
    const float* __restrict__ qw, const float* __restrict__ qb, float theta,
    const int* __restrict__ flag, const float* __restrict__ dis,
    float* __restrict__ Hout, uint32_t* __restrict__ Hq,
    float* __restrict__ Sc, float* __restrict__ S)
{
    __shared__ __align__(16) uint16_t sAhi[64 * 64];    // 8 KiB
    __shared__ __align__(16) uint16_t sAlo[64 * 64];    // 8 KiB
    __shared__ __align__(16) uint16_t sBhi[128 * 64];   // 16 KiB
    __shared__ __align__(16) uint16_t sBlo[128 * 64];   // 16 KiB -> 48 KiB, 3 blk/CU

    if (*flag)
        gemm_body<KD, MODE, WH, WQ, 1>(Araw, WThi, WTlo, bias, gamma, beta, qw, qb,
                                       theta, dis, Hout, Hq, Sc, S, sAhi, sAlo, sBhi, sBlo);
    else
        gemm_body<KD, MODE, WH, WQ, 0>(Araw, WThi, WTlo, bias, gamma, beta, qw, qb,
                                       theta, dis, Hout, Hq, Sc, S, sAhi, sAlo, sBhi, sBlo);
}

// ---------------- classifier (fp32 in, dtype-flag out) ----------------

__global__ __launch_bounds__(256) void k_cls(const float* __restrict__ H,
                                             const float* __restrict__ Wc,
                                             const float* __restrict__ bc,
                                             const int* __restrict__ flag,
                                             void* __restrict__ out) {
    __shared__ float wS[128][8];
    int tid = threadIdx.x;
    for (int idx = tid; idx < 128 * 7; idx += 256) wS[idx / 7][idx % 7] = Wc[idx];
    __syncthreads();
    int isf32 = *flag;
    int gid = blockIdx.x * 256 + tid;
    int n = gid >> 3, j = gid & 7;
    if (n >= N_NODES || j >= OUT_DIM) return;
    const float4* hr = (const float4*)(H + (size_t)n * 128);
    float acc = bc[j];
#pragma unroll
    for (int k4 = 0; k4 < 32; k4++) {
        float4 h4 = hr[k4];
        acc += h4.x * wS[4 * k4][j]     + h4.y * wS[4 * k4 + 1][j]
             + h4.z * wS[4 * k4 + 2][j] + h4.w * wS[4 * k4 + 3][j];
    }
    size_t oi = (size_t)n * OUT_DIM + j;
    if (isf32) ((float*)out)[oi] = acc;
    else       ((uint16_t*)out)[oi] = f2bf(acc);
}

// ---------------- launch ----------------

extern "C" void kernel_launch(void* const* d_in, const int* in_sizes, int n_in,
                              void* d_out, int out_size, void* d_ws, size_t ws_size,
                              hipStream_t stream) {
    const void* x_raw = d_in[0];
    const int*  ei    = (const int*)d_in[1];
    const int* row = ei;
    const int* col = ei + N_EDGES;

    char* ws = (char*)d_ws;
    size_t off = 0;
    auto alloc = [&](size_t b) { void* p = ws + off; off = (off + b + 255) & ~(size_t)255; return p; };
    int*      flag = (int*)alloc(4);
    float*    stgf = (float*)alloc((size_t)99744 * 4);
    int*      rp   = (int*)alloc(((size_t)N_NODES + 1) * 4);
    float*    dis  = (float*)alloc((size_t)N_NODES * 4);
    int*      hist = (int*)alloc((size_t)NCH * NBK * 4);          // 613 KB
    int*      totB = (int*)alloc((size_t)NBK * 4);
    int*      boffB= (int*)alloc(((size_t)NBK + 1) * 4);
    int*      edc  = (int*)alloc((size_t)N_EDGES * 4);            // CSR cols (4B)
    float*    h0   = (float*)alloc((size_t)N_NODES * HID * 4);
    float*    sup  = (float*)alloc((size_t)N_NODES * HID * 4);    // also final h (in-place)
    uint32_t* hq   = (uint32_t*)alloc((size_t)N_NODES * 64 * 4);  // int16 mirror
    float*    Scq  = (float*)alloc((size_t)N_NODES * 4);          // quant scale * dis
    float*    Sg   = (float*)alloc((size_t)N_NODES * 4);          // gate sigmoid
    uint16_t* wpThi = (uint16_t*)alloc((size_t)32768 * 2);
    uint16_t* wpTlo = (uint16_t*)alloc((size_t)32768 * 2);
    uint16_t* cwThi = (uint16_t*)alloc((size_t)65536 * 2);
    uint16_t* cwTlo = (uint16_t*)alloc((size_t)65536 * 2);
    uint32_t* ebp  = (uint32_t*)h0;   // bucket-sorted packed edges (6.4MB) alias h0

    const float* bp  = stgf + 32768;
    const float* gm  = stgf + 32896;
    const float* bt  = stgf + 33024;
    const float* qw  = stgf + 33152;
    const float* qb  = stgf + 33280;
    const float* clw = stgf + 98832;
    const float* clb = stgf + 99728;

    k_detect<<<1, 64, 0, stream>>>((const uint32_t*)d_in[2], flag);
    k_cvt<<<(99720 + 255) / 256, 256, 0, stream>>>(d_in[2], d_in[3], d_in[4], d_in[5], d_in[6],
                                                   d_in[7], d_in[8], d_in[9], d_in[10], stgf, flag);
    k_wsplit<<<(98304 + 255) / 256, 256, 0, stream>>>(stgf, wpThi, wpTlo, cwThi, cwTlo);

    k_hist<<<NCH, 256, 0, stream>>>(row, hist);
    k_hscan<<<NBK, 128, 0, stream>>>(hist, totB);
    k_bscan<<<1, 256, 0, stream>>>(totB, boffB, rp);
    k_sortscat<<<NCH, 256, 0, stream>>>(row, col, hist, boffB, ebp);
    k_bfin<<<NBK, 256, 0, stream>>>(ebp, boffB, rp, dis, edc);

    const int gemm_grid = (N_NODES + 63) / 64;   // 1563
    k_gemm_mfma<IN_DIM, 0, 1, 1><<<gemm_grid, 256, 0, stream>>>(
        x_raw, wpThi, wpTlo, bp, gm, bt, qw, qb, 0.f, flag, dis, h0, hq, Scq, Sg);

    for (int i = 0; i < N_LAYERS; i++) {
        k_spmm<<<(N_NODES + 3) / 4, 256, 0, stream>>>(hq, Scq, h0, rp, edc, Sg, dis, sup);
        float theta = 0.5f / (float)(i + 1);
        const uint16_t* whi = cwThi + (size_t)i * 16384;
        const uint16_t* wlo = cwTlo + (size_t)i * 16384;
        if (i < N_LAYERS - 1) {
            k_gemm_mfma<HID, 1, 0, 1><<<gemm_grid, 256, 0, stream>>>(
                sup, whi, wlo, nullptr, gm, bt, qw, qb, theta, flag, dis, sup, hq, Scq, Sg);
        } else {
            k_gemm_mfma<HID, 1, 1, 0><<<gemm_grid, 256, 0, stream>>>(
                sup, whi, wlo, nullptr, gm, bt, qw, qb, theta, flag, dis, sup, hq, Scq, Sg);
        }
    }
    k_cls<<<((size_t)N_NODES * 8 + 255) / 256, 256, 0, stream>>>(sup, clw, clb, flag, d_out);
}

// Round 5
// 834.579 us; speedup vs baseline: 1.0595x; 1.0595x over previous
//
#include <hip/hip_runtime.h>
#include <hip/hip_bf16.h>
#include <hip/hip_fp16.h>
#include <stdint.h>

#define N_NODES 100000
#define N_EDGES 1600000
#define IN_DIM 256
#define HID 128
#define N_LAYERS 4
#define OUT_DIM 7
#define LN_EPS 1e-5f

// counting-sort CSR build
#define BSHIFT 6
#define BROWS 64
#define NBK 1563                  // ceil(100000/64) buckets of 64 rows
#define CHUNK 16384               // edges per sort block
#define NCH ((N_EDGES + CHUNK - 1) / CHUNK)   // 98 (must be <= 128 for k_hscan)

typedef __attribute__((ext_vector_type(8))) short bf16x8;
typedef __attribute__((ext_vector_type(4))) float f32x4;

__device__ inline float bf2f1(uint16_t u) {
    union { uint32_t i; float f; } a; a.i = ((uint32_t)u) << 16; return a.f;
}
__device__ inline uint16_t f2bf(float f) {
    union { float f; uint32_t i; } a; a.f = f;
    uint32_t lsb = (a.i >> 16) & 1u;
    a.i += 0x7fffu + lsb;          // round-to-nearest-even
    return (uint16_t)(a.i >> 16);
}
__device__ inline uint32_t packq(float a, float b, float qinv) {
    int qa = __float2int_rn(a * qinv);
    int qb = __float2int_rn(b * qinv);
    return ((uint32_t)(uint16_t)(short)qa) | (((uint32_t)(uint16_t)(short)qb) << 16);
}

// fragment-order W pack index: value at (k, c) of W^(KD x 128)
__device__ __host__ inline int wpack_idx(int k, int c) {
    int kc = k >> 6, ks = (k >> 5) & 1, lg = (k >> 3) & 3, e = k & 7;
    int ct = c >> 4, li = c & 15;
    return ((((kc * 2 + ks) * 8 + ct) * 16 + li) * 4 + lg) * 8 + e;
}

// ---------------- dtype detection (device fallback) ----------------
__global__ void k_detect(const uint32_t* __restrict__ W, int* __restrict__ flag) {
    if (threadIdx.x == 0 && blockIdx.x == 0) {
        int cnt = 0;
        for (int i = 0; i < 64; i++) {
            uint32_t lo = W[i] & 0xffffu;
            uint32_t ex = (lo >> 7) & 0xff;
            if (ex >= 0x60 && ex < 0x7c) cnt++;
        }
        *flag = (cnt < 32) ? 1 : 0;   // 1 = fp32 inputs, 0 = bf16 inputs
    }
}
__global__ void k_setflag(int* __restrict__ flag, int v) {
    if (threadIdx.x == 0) *flag = v;
}

// ---------------- weight canonicalization (all weights -> fp32 staged) ----------------
__global__ __launch_bounds__(256) void k_cvt(const void* a0, const void* a1, const void* a2,
                                             const void* a3, const void* a4, const void* a5,
                                             const void* a6, const void* a7, const void* a8,
                                             float* __restrict__ dst, const int* __restrict__ flag) {
    int t = blockIdx.x * 256 + threadIdx.x;
    if (t >= 99720) return;
    const void* src; int i; int off;
    if      (t < 32768) { src = a0; i = t;         off = 0;     }   // W_proj 256x128
    else if (t < 32896) { src = a1; i = t - 32768; off = 32768; }   // b_proj 128
    else if (t < 33024) { src = a2; i = t - 32896; off = 32896; }   // gamma 128
    else if (t < 33152) { src = a3; i = t - 33024; off = 33024; }   // beta 128
    else if (t < 33280) { src = a4; i = t - 33152; off = 33152; }   // q_w 128
    else if (t < 33281) { src = a5; i = t - 33280; off = 33280; }   // q_b 1
    else if (t < 98817) { src = a6; i = t - 33281; off = 33296; }   // conv_w 4x128x128
    else if (t < 99713) { src = a7; i = t - 98817; off = 98832; }   // cls_w 128x7
    else                { src = a8; i = t - 99713; off = 99728; }   // cls_b 7
    float v;
    if (*flag) v = ((const float*)src)[i];
    else       v = bf2f1(((const uint16_t*)src)[i]);
    dst[off + i] = v;
}

// ---------------- split-bf16 weight prep, fragment-ordered ----------------
// wpk*: [256x128] W_proj packed; cwk*: [L][128x128] conv_w packed.
__global__ __launch_bounds__(256) void k_wsplit(const float* __restrict__ stg,
                                                uint16_t* __restrict__ wpkhi, uint16_t* __restrict__ wpklo,
                                                uint16_t* __restrict__ cwkhi, uint16_t* __restrict__ cwklo) {
    int t = blockIdx.x * 256 + threadIdx.x;
    if (t >= 32768 + 65536) return;
    float v; size_t dst; uint16_t *ha, *la;
    if (t < 32768) {
        int k = t >> 7, c = t & 127;
        v = stg[t];
        dst = (size_t)wpack_idx(k, c); ha = wpkhi; la = wpklo;
    } else {
        int u = t - 32768;
        int L = u >> 14, rem = u & 16383;
        int k = rem >> 7, c = rem & 127;
        v = stg[33296 + u];
        dst = (size_t)L * 16384 + wpack_idx(k, c); ha = cwkhi; la = cwklo;
    }
    uint16_t hb = f2bf(v);
    uint16_t lb = f2bf(v - bf2f1(hb));
    ha[dst] = hb; la[dst] = lb;
}

// ---------------- graph prep: atomic-free counting-sort CSR build ----------------

__global__ __launch_bounds__(256) void k_hist(const int* __restrict__ row, int* __restrict__ hist) {
    __shared__ int lh[NBK];
    int b = blockIdx.x, tid = threadIdx.x;
    for (int i = tid; i < NBK; i += 256) lh[i] = 0;
    __syncthreads();
    int e0 = b * CHUNK;
    int lim = N_EDGES - e0; if (lim > CHUNK) lim = CHUNK;
    for (int i = tid; i < lim; i += 256) atomicAdd(&lh[row[e0 + i] >> BSHIFT], 1);
    __syncthreads();
    for (int i = tid; i < NBK; i += 256) hist[(size_t)b * NBK + i] = lh[i];
}

__global__ __launch_bounds__(128) void k_hscan(int* __restrict__ hist, int* __restrict__ totB) {
    __shared__ int s[128];
    int bkt = blockIdx.x, t = threadIdx.x;
    int v = (t < NCH) ? hist[(size_t)t * NBK + bkt] : 0;
    s[t] = v;
    __syncthreads();
    for (int off = 1; off < 128; off <<= 1) {
        int add = (t >= off) ? s[t - off] : 0;
        __syncthreads();
        s[t] += add;
        __syncthreads();
    }
    if (t < NCH) hist[(size_t)t * NBK + bkt] = s[t] - v;   // exclusive within bucket
    if (t == 127) totB[bkt] = s[127];
}

__global__ __launch_bounds__(256) void k_bscan(const int* __restrict__ totB,
                                               int* __restrict__ boffB, int* __restrict__ rp) {
    __shared__ int ps[256];
    int t = threadIdx.x;
    const int STRIP = 7;                     // 256*7 = 1792 >= NBK
    int base = t * STRIP;
    int loc[STRIP]; int sum = 0;
#pragma unroll
    for (int j = 0; j < STRIP; j++) {
        int idx = base + j;
        int v = (idx < NBK) ? totB[idx] : 0;
        loc[j] = sum; sum += v;
    }
    ps[t] = sum;
    __syncthreads();
    int v = ps[t];
    for (int off = 1; off < 256; off <<= 1) {
        int add = (t >= off) ? ps[t - off] : 0;
        __syncthreads();
        ps[t] += add;
        __syncthreads();
    }
    int excl = ps[t] - v;
#pragma unroll
    for (int j = 0; j < STRIP; j++) {
        int idx = base + j;
        if (idx < NBK) boffB[idx] = excl + loc[j];
    }
    if (t == 0) { boffB[NBK] = N_EDGES; rp[N_NODES] = N_EDGES; }
}

__global__ __launch_bounds__(256) void k_sortscat(const int* __restrict__ row, const int* __restrict__ col,
                                                  const int* __restrict__ hist, const int* __restrict__ boffB,
                                                  uint32_t* __restrict__ ebp) {
    __shared__ int dbase[NBK];
    __shared__ int lcnt[NBK];
    int b = blockIdx.x, tid = threadIdx.x;
    for (int i = tid; i < NBK; i += 256) {
        dbase[i] = boffB[i] + hist[(size_t)b * NBK + i];
        lcnt[i] = 0;
    }
    __syncthreads();
    int e0 = b * CHUNK;
    int lim = N_EDGES - e0; if (lim > CHUNK) lim = CHUNK;
    for (int i = tid; i < lim; i += 256) {
        int r = row[e0 + i], c = col[e0 + i];
        int bk = r >> BSHIFT;
        int rank = atomicAdd(&lcnt[bk], 1);
        ebp[dbase[bk] + rank] = ((uint32_t)(r & (BROWS - 1)) << 17) | (uint32_t)c;
    }
}

__global__ __launch_bounds__(256) void k_bfin(const uint32_t* __restrict__ ebp, const int* __restrict__ boffB,
                                              int* __restrict__ rp, float* __restrict__ dis,
                                              int* __restrict__ edc) {
    __shared__ int ldeg[BROWS];
    __shared__ int lcur[BROWS];
    int b = blockIdx.x, tid = threadIdx.x;
    int base = boffB[b];
    int n = boffB[b + 1] - base;
    if (tid < BROWS) ldeg[tid] = 0;
    __syncthreads();
    for (int i = tid; i < n; i += 256) atomicAdd(&ldeg[ebp[base + i] >> 17], 1);
    __syncthreads();
    if (tid == 0) {
        int run = 0;
        for (int r = 0; r < BROWS; r++) { int d = ldeg[r]; lcur[r] = run; run += d; }
    }
    __syncthreads();
    int row0 = b << BSHIFT;
    if (tid < BROWS && row0 + tid < N_NODES) {
        int d = ldeg[tid];
        rp[row0 + tid]  = base + lcur[tid];
        dis[row0 + tid] = rsqrtf((float)(d > 0 ? d : 1));
    }
    __syncthreads();   // rp/dis read lcur before scatter mutates it
    for (int i = tid; i < n; i += 256) {
        uint32_t pk = ebp[base + i];
        int r = pk >> 17;
        int pos = atomicAdd(&lcur[r], 1);
        edc[base + pos] = (int)(pk & 0x1FFFFu);
    }
}

// ---------------- fused SpMM + blend ----------------
// one wave per node; lane holds cols {lane, lane+64}; 8-deep gather unroll.

__global__ __launch_bounds__(256) void k_spmm(const uint32_t* __restrict__ Hq,
                                              const float* __restrict__ ScD,
                                              const float* __restrict__ H0,
                                              const int* __restrict__ rp,
                                              const int* __restrict__ edc,
                                              const float* __restrict__ S,
                                              const float* __restrict__ dis,
                                              float* __restrict__ Sup) {
    int wid  = (blockIdx.x * 256 + threadIdx.x) >> 6;
    int lane = threadIdx.x & 63;
    if (wid >= N_NODES) return;

    float s  = S[wid];
    float dr = dis[wid];
    float h0x = H0[(size_t)wid * 128 + lane];
    float h0y = H0[(size_t)wid * 128 + 64 + lane];

    int p0 = rp[wid], p1 = rp[wid + 1];
    float ax = 0.f, ay = 0.f;
    int p = p0;
    for (; p + 8 <= p1; p += 8) {
        int c[8]; uint32_t u[8]; float w[8];
#pragma unroll
        for (int j = 0; j < 8; j++) c[j] = edc[p + j];
#pragma unroll
        for (int j = 0; j < 8; j++) u[j] = Hq[(size_t)c[j] * 64 + lane];
#pragma unroll
        for (int j = 0; j < 8; j++) w[j] = ScD[c[j]];
#pragma unroll
        for (int j = 0; j < 8; j++) {
            ax += w[j] * (float)((int)(u[j] << 16) >> 16);
            ay += w[j] * (float)((int)u[j] >> 16);
        }
    }
    for (; p + 4 <= p1; p += 4) {
        int c[4]; uint32_t u[4]; float w[4];
#pragma unroll
        for (int j = 0; j < 4; j++) c[j] = edc[p + j];
#pragma unroll
        for (int j = 0; j < 4; j++) u[j] = Hq[(size_t)c[j] * 64 + lane];
#pragma unroll
        for (int j = 0; j < 4; j++) w[j] = ScD[c[j]];
#pragma unroll
        for (int j = 0; j < 4; j++) {
            ax += w[j] * (float)((int)(u[j] << 16) >> 16);
            ay += w[j] * (float)((int)u[j] >> 16);
        }
    }
    for (; p < p1; p++) {
        int c = edc[p];
        uint32_t u = Hq[(size_t)c * 64 + lane];
        float w = ScD[c];
        ax += w * (float)((int)(u << 16) >> 16);
        ay += w * (float)((int)u >> 16);
    }
    float f = (1.f - s) * dr;
    Sup[(size_t)wid * 128 + lane]      = f * ax + s * h0x;
    Sup[(size_t)wid * 128 + 64 + lane] = f * ay + s * h0y;
}

// ---------------- LDS-free split-bf16 MFMA GEMM + fused LN/gate/quant ----------------
// Block = 64 rows, 4 independent waves (NO barriers, NO LDS). Wave wv owns rows wv*16+li.
// A loaded directly from global per-wave (rows are wave-exclusive), hi/lo split in-register.
// B loaded from fragment-packed W (wpack_idx): 16B coalesced, L1/L2-hot (shared by all blocks).
// C layout: col = lane&15, row = (lane>>4)*4 + reg.  Split: C = Ah*Wh + Ah*Wl + Al*Wh.
// WF = inputs-are-fp32 (compile-time); guard exits if runtime flag mismatches.
// NOTE: Hout may alias Araw for MODE 1 (rows are wave-exclusive across the grid).

template <int KD, int MODE, int WH, int WQ, int WF>
__global__ __launch_bounds__(256, 4) void k_gemm(
    const void* __restrict__ Araw,       // [N][KD] fp32 (or bf16 if MODE0 && WF==0)
    const uint16_t* __restrict__ Whi,    // packed hi plane
    const uint16_t* __restrict__ Wlo,    // packed lo plane
    const float* __restrict__ bias, const float* __restrict__ gamma,
    const float* __restrict__ beta, const float* __restrict__ qw,
    const float* __restrict__ qb, float theta, const int* __restrict__ flag,
    const float* __restrict__ dis,
    float* __restrict__ Hout, uint32_t* __restrict__ Hq,
    float* __restrict__ Sc, float* __restrict__ S)
{
    if (*flag != WF) return;             // guarded dual-launch fallback
    constexpr int F32A = (MODE == 0) ? WF : 1;
    constexpr int NC = KD / 64;

    const int tid  = threadIdx.x;
    const int lane = tid & 63;
    const int wv   = tid >> 6;
    const int li   = lane & 15;
    const int lg   = lane >> 4;
    const size_t row0 = (size_t)blockIdx.x * 64;
    size_t arow = row0 + wv * 16 + li;
    if (arow >= N_NODES) arow = N_NODES - 1;   // clamp (epilogue guards writes)

    f32x4 acc[8];
#pragma unroll
    for (int ct = 0; ct < 8; ct++) acc[ct] = (f32x4){0.f, 0.f, 0.f, 0.f};

#pragma unroll
    for (int kc = 0; kc < NC; kc++) {
#pragma unroll
        for (int ks = 0; ks < 2; ks++) {
            const int koff = kc * 64 + ks * 32 + lg * 8;
            bf16x8 ah, al;
            if constexpr (F32A) {
                const float* ap = (const float*)Araw + arow * KD + koff;
                float4 u0 = *(const float4*)ap;
                float4 u1 = *(const float4*)(ap + 4);
                float f[8] = {u0.x, u0.y, u0.z, u0.w, u1.x, u1.y, u1.z, u1.w};
#pragma unroll
                for (int j = 0; j < 8; j++) {
                    uint16_t hb = f2bf(f[j]);
                    ah[j] = (short)hb;
                    al[j] = (short)f2bf(f[j] - bf2f1(hb));
                }
            } else {
                ah = *(const bf16x8*)((const uint16_t*)Araw + arow * KD + koff);
            }
            const size_t wb0 = (size_t)(kc * 2 + ks) * 4096 + (size_t)li * 32 + (size_t)lg * 8;
#pragma unroll
            for (int ct = 0; ct < 8; ct++) {
                const size_t wb = wb0 + (size_t)ct * 512;
                bf16x8 bh = *(const bf16x8*)(Whi + wb);
                acc[ct] = __builtin_amdgcn_mfma_f32_16x16x32_bf16(ah, bh, acc[ct], 0, 0, 0);
                if constexpr (F32A)
                    acc[ct] = __builtin_amdgcn_mfma_f32_16x16x32_bf16(al, bh, acc[ct], 0, 0, 0);
                if constexpr (WF) {
                    bf16x8 bl = *(const bf16x8*)(Wlo + wb);
                    acc[ct] = __builtin_amdgcn_mfma_f32_16x16x32_bf16(ah, bl, acc[ct], 0, 0, 0);
                }
            }
        }
    }

    // ---- epilogue: per (lane, reg) one row, cols {ct*16+li} ----
    float gm[8], bt[8], qv[8], bi[8];
#pragma unroll
    for (int ct = 0; ct < 8; ct++) {
        int c = ct * 16 + li;
        gm[ct] = gamma[c]; bt[ct] = beta[c]; qv[ct] = qw[c];
        bi[ct] = (MODE == 0) ? bias[c] : 0.f;
    }
    const float qbv = qb[0];
    const float om  = 1.f - theta;
    const float* Af = (const float*)Araw;

#pragma unroll
    for (int r = 0; r < 4; r++) {
        int rowl  = wv * 16 + lg * 4 + r;
        size_t rg = row0 + rowl;
        size_t rc = (rg < N_NODES) ? rg : (N_NODES - 1);
        float v[8];
        if (MODE == 0) {
#pragma unroll
            for (int ct = 0; ct < 8; ct++) v[ct] = acc[ct][r] + bi[ct];
        } else {
#pragma unroll
            for (int ct = 0; ct < 8; ct++) {
                float sv = Af[rc * KD + ct * 16 + li];   // support re-read (L1-hot)
                float o  = theta * acc[ct][r] + om * sv;
                v[ct] = o > 0.f ? o : 0.f;
            }
        }
        float sum = 0.f, sq = 0.f;
#pragma unroll
        for (int ct = 0; ct < 8; ct++) { sum += v[ct]; sq += v[ct] * v[ct]; }
        sum += __shfl_xor(sum, 1); sum += __shfl_xor(sum, 2);
        sum += __shfl_xor(sum, 4); sum += __shfl_xor(sum, 8);
        sq  += __shfl_xor(sq, 1);  sq  += __shfl_xor(sq, 2);
        sq  += __shfl_xor(sq, 4);  sq  += __shfl_xor(sq, 8);
        float mu  = sum * (1.f / 128.f);
        float var = fmaxf(sq * (1.f / 128.f) - mu * mu, 0.f);
        float rs  = rsqrtf(var + LN_EPS);
        float y[8];
#pragma unroll
        for (int ct = 0; ct < 8; ct++) y[ct] = gm[ct] * (v[ct] - mu) * rs + bt[ct];

        if (WQ) {
            float zd = 0.f, am = 0.f;
#pragma unroll
            for (int ct = 0; ct < 8; ct++) { zd += y[ct] * qv[ct]; am = fmaxf(am, fabsf(y[ct])); }
            zd += __shfl_xor(zd, 1); zd += __shfl_xor(zd, 2);
            zd += __shfl_xor(zd, 4); zd += __shfl_xor(zd, 8);
            am = fmaxf(am, __shfl_xor(am, 1)); am = fmaxf(am, __shfl_xor(am, 2));
            am = fmaxf(am, __shfl_xor(am, 4)); am = fmaxf(am, __shfl_xor(am, 8));
            float amc  = fmaxf(am, 1e-20f);
            float qinv = 32767.f / amc;
            if (rg < N_NODES) {
                uint32_t* mq = Hq + rg * 64;
#pragma unroll
                for (int ct = 0; ct < 4; ct++)
                    mq[ct * 16 + li] = packq(y[ct], y[ct + 4], qinv);  // pair (c, c+64)
                if (li == 0) {
                    Sc[rg] = amc * (1.f / 32767.f) * dis[rg];   // fold dis[col] into scale
                    S[rg]  = 1.f / (1.f + __expf(-(zd + qbv - 1.f)));
                }
            }
        }
        if (WH && rg < N_NODES) {
            float* dst = Hout + rg * 128;
#pragma unroll
            for (int ct = 0; ct < 8; ct++) dst[ct * 16 + li] = y[ct];
        }
    }
}

// ---------------- classifier (fp32 in, dtype-flag out) ----------------

__global__ __launch_bounds__(256) void k_cls(const float* __restrict__ H,
                                             const float* __restrict__ Wc,
                                             const float* __restrict__ bc,
                                             const int* __restrict__ flag,
                                             void* __restrict__ out) {
    __shared__ float wS[128][8];
    int tid = threadIdx.x;
    for (int idx = tid; idx < 128 * 7; idx += 256) wS[idx / 7][idx % 7] = Wc[idx];
    __syncthreads();
    int isf32 = *flag;
    int gid = blockIdx.x * 256 + tid;
    int n = gid >> 3, j = gid & 7;
    if (n >= N_NODES || j >= OUT_DIM) return;
    const float4* hr = (const float4*)(H + (size_t)n * 128);
    float acc = bc[j];
#pragma unroll
    for (int k4 = 0; k4 < 32; k4++) {
        float4 h4 = hr[k4];
        acc += h4.x * wS[4 * k4][j]     + h4.y * wS[4 * k4 + 1][j]
             + h4.z * wS[4 * k4 + 2][j] + h4.w * wS[4 * k4 + 3][j];
    }
    size_t oi = (size_t)n * OUT_DIM + j;
    if (isf32) ((float*)out)[oi] = acc;
    else       ((uint16_t*)out)[oi] = f2bf(acc);
}

// ---------------- launch ----------------

extern "C" void kernel_launch(void* const* d_in, const int* in_sizes, int n_in,
                              void* d_out, int out_size, void* d_ws, size_t ws_size,
                              hipStream_t stream) {
    const void* x_raw = d_in[0];
    const int*  ei    = (const int*)d_in[1];
    const int* row = ei;
    const int* col = ei + N_EDGES;

    char* ws = (char*)d_ws;
    size_t off = 0;
    auto alloc = [&](size_t b) { void* p = ws + off; off = (off + b + 255) & ~(size_t)255; return p; };
    int*      flag = (int*)alloc(4);
    float*    stgf = (float*)alloc((size_t)99744 * 4);
    int*      rp   = (int*)alloc(((size_t)N_NODES + 1) * 4);
    float*    dis  = (float*)alloc((size_t)N_NODES * 4);
    int*      hist = (int*)alloc((size_t)NCH * NBK * 4);          // 613 KB
    int*      totB = (int*)alloc((size_t)NBK * 4);
    int*      boffB= (int*)alloc(((size_t)NBK + 1) * 4);
    int*      edc  = (int*)alloc((size_t)N_EDGES * 4);            // CSR cols (4B)
    float*    h0   = (float*)alloc((size_t)N_NODES * HID * 4);
    float*    sup  = (float*)alloc((size_t)N_NODES * HID * 4);    // also final h (in-place)
    uint32_t* hq   = (uint32_t*)alloc((size_t)N_NODES * 64 * 4);  // int16 mirror
    float*    Scq  = (float*)alloc((size_t)N_NODES * 4);          // quant scale * dis
    float*    Sg   = (float*)alloc((size_t)N_NODES * 4);          // gate sigmoid
    uint16_t* wpkhi = (uint16_t*)alloc((size_t)32768 * 2);        // W_proj packed hi
    uint16_t* wpklo = (uint16_t*)alloc((size_t)32768 * 2);
    uint16_t* cwkhi = (uint16_t*)alloc((size_t)65536 * 2);        // conv_w packed hi (4 layers)
    uint16_t* cwklo = (uint16_t*)alloc((size_t)65536 * 2);
    uint32_t* ebp  = (uint32_t*)h0;   // bucket-sorted packed edges (6.4MB) alias h0

    const float* bp  = stgf + 32768;
    const float* gm  = stgf + 32896;
    const float* bt  = stgf + 33024;
    const float* qw  = stgf + 33152;
    const float* qb  = stgf + 33280;
    const float* clw = stgf + 98832;
    const float* clb = stgf + 99728;

    // host-side dtype detection from byte sizes; -1 = unknown -> guarded dual launch
    int hostflag = -1;
    if (in_sizes && n_in >= 3) {
        if      (in_sizes[2] == 32768 * 4) hostflag = 1;
        else if (in_sizes[2] == 32768 * 2) hostflag = 0;
        else if (in_sizes[0] == N_NODES * IN_DIM * 4) hostflag = 1;
        else if (in_sizes[0] == N_NODES * IN_DIM * 2) hostflag = 0;
    }
    if (hostflag >= 0) k_setflag<<<1, 64, 0, stream>>>(flag, hostflag);
    else               k_detect<<<1, 64, 0, stream>>>((const uint32_t*)d_in[2], flag);

    k_cvt<<<(99720 + 255) / 256, 256, 0, stream>>>(d_in[2], d_in[3], d_in[4], d_in[5], d_in[6],
                                                   d_in[7], d_in[8], d_in[9], d_in[10], stgf, flag);
    k_wsplit<<<(98304 + 255) / 256, 256, 0, stream>>>(stgf, wpkhi, wpklo, cwkhi, cwklo);

    k_hist<<<NCH, 256, 0, stream>>>(row, hist);
    k_hscan<<<NBK, 128, 0, stream>>>(hist, totB);
    k_bscan<<<1, 256, 0, stream>>>(totB, boffB, rp);
    k_sortscat<<<NCH, 256, 0, stream>>>(row, col, hist, boffB, ebp);
    k_bfin<<<NBK, 256, 0, stream>>>(ebp, boffB, rp, dis, edc);

    const int gemm_grid = (N_NODES + 63) / 64;   // 1563
    if (hostflag != 0)
        k_gemm<IN_DIM, 0, 1, 1, 1><<<gemm_grid, 256, 0, stream>>>(
            x_raw, wpkhi, wpklo, bp, gm, bt, qw, qb, 0.f, flag, dis, h0, hq, Scq, Sg);
    if (hostflag != 1)
        k_gemm<IN_DIM, 0, 1, 1, 0><<<gemm_grid, 256, 0, stream>>>(
            x_raw, wpkhi, wpklo, bp, gm, bt, qw, qb, 0.f, flag, dis, h0, hq, Scq, Sg);

    for (int i = 0; i < N_LAYERS; i++) {
        k_spmm<<<(N_NODES + 3) / 4, 256, 0, stream>>>(hq, Scq, h0, rp, edc, Sg, dis, sup);
        float theta = 0.5f / (float)(i + 1);
        const uint16_t* whi = cwkhi + (size_t)i * 16384;
        const uint16_t* wlo = cwklo + (size_t)i * 16384;
        if (i < N_LAYERS - 1) {
            if (hostflag != 0)
                k_gemm<HID, 1, 0, 1, 1><<<gemm_grid, 256, 0, stream>>>(
                    sup, whi, wlo, nullptr, gm, bt, qw, qb, theta, flag, dis, sup, hq, Scq, Sg);
            if (hostflag != 1)
                k_gemm<HID, 1, 0, 1, 0><<<gemm_grid, 256, 0, stream>>>(
                    sup, whi, wlo, nullptr, gm, bt, qw, qb, theta, flag, dis, sup, hq, Scq, Sg);
        } else {
            if (hostflag != 0)
                k_gemm<HID, 1, 1, 0, 1><<<gemm_grid, 256, 0, stream>>>(
                    sup, whi, wlo, nullptr, gm, bt, qw, qb, theta, flag, dis, sup, hq, Scq, Sg);
            if (hostflag != 1)
                k_gemm<HID, 1, 1, 0, 0><<<gemm_grid, 256, 0, stream>>>(
                    sup, whi, wlo, nullptr, gm, bt, qw, qb, theta, flag, dis, sup, hq, Scq, Sg);
        }
    }
    k_cls<<<((size_t)N_NODES * 8 + 255) / 256, 256, 0, stream>>>(sup, clw, clb, flag, d_out);
}

// Round 6
// 750.278 us; speedup vs baseline: 1.1785x; 1.1124x over previous
//
#include <hip/hip_runtime.h>
#include <hip/hip_bf16.h>
#include <hip/hip_fp16.h>
#include <stdint.h>

#define N_NODES 100000
#define N_EDGES 1600000
#define IN_DIM 256
#define HID 128
#define N_LAYERS 4
#define OUT_DIM 7
#define LN_EPS 1e-5f

// counting-sort CSR build
#define BSHIFT 6
#define BROWS 64
#define NBK 1563                  // ceil(100000/64) buckets of 64 rows
#define CHUNK 16384               // edges per sort block
#define NCH ((N_EDGES + CHUNK - 1) / CHUNK)   // 98 (must be <= 128 for k_hscan)

typedef __attribute__((ext_vector_type(8))) short bf16x8;
typedef __attribute__((ext_vector_type(4))) float f32x4;

__device__ inline float bf2f1(uint16_t u) {
    union { uint32_t i; float f; } a; a.i = ((uint32_t)u) << 16; return a.f;
}
__device__ inline uint16_t f2bf(float f) {
    union { float f; uint32_t i; } a; a.f = f;
    uint32_t lsb = (a.i >> 16) & 1u;
    a.i += 0x7fffu + lsb;          // round-to-nearest-even
    return (uint16_t)(a.i >> 16);
}
__device__ inline uint32_t packq(float a, float b, float qinv) {
    int qa = __float2int_rn(a * qinv);
    int qb = __float2int_rn(b * qinv);
    return ((uint32_t)(uint16_t)(short)qa) | (((uint32_t)(uint16_t)(short)qb) << 16);
}

// fragment-order W pack: lane-linear so LDS B-frag read is one contiguous 16B.
// element (k, c) of W[KD][128] -> ((ksg*8 + ct)*64 + lane)*8 + e
//   ksg = k>>5 (32-K step), lg = (k>>3)&3, e = k&7, ct = c>>4, li = c&15, lane = lg*16+li
__device__ __host__ inline int wpack_idx(int k, int c) {
    int ksg = k >> 5, lg = (k >> 3) & 3, e = k & 7;
    int ct = c >> 4, li = c & 15;
    return ((ksg * 8 + ct) * 64 + (lg * 16 + li)) * 8 + e;
}

// ---------------- dtype detection ----------------
__global__ void k_detect(const uint32_t* __restrict__ W, int* __restrict__ flag) {
    if (threadIdx.x == 0 && blockIdx.x == 0) {
        int cnt = 0;
        for (int i = 0; i < 64; i++) {
            uint32_t lo = W[i] & 0xffffu;
            uint32_t ex = (lo >> 7) & 0xff;
            if (ex >= 0x60 && ex < 0x7c) cnt++;
        }
        *flag = (cnt < 32) ? 1 : 0;   // 1 = fp32 inputs, 0 = bf16 inputs
    }
}
__global__ void k_setflag(int* __restrict__ flag, int v) {
    if (threadIdx.x == 0) *flag = v;
}

// ---------------- weight canonicalization (all weights -> fp32 staged) ----------------
__global__ __launch_bounds__(256) void k_cvt(const void* a0, const void* a1, const void* a2,
                                             const void* a3, const void* a4, const void* a5,
                                             const void* a6, const void* a7, const void* a8,
                                             float* __restrict__ dst, const int* __restrict__ flag) {
    int t = blockIdx.x * 256 + threadIdx.x;
    if (t >= 99720) return;
    const void* src; int i; int off;
    if      (t < 32768) { src = a0; i = t;         off = 0;     }   // W_proj 256x128
    else if (t < 32896) { src = a1; i = t - 32768; off = 32768; }   // b_proj 128
    else if (t < 33024) { src = a2; i = t - 32896; off = 32896; }   // gamma 128
    else if (t < 33152) { src = a3; i = t - 33024; off = 33024; }   // beta 128
    else if (t < 33280) { src = a4; i = t - 33152; off = 33152; }   // q_w 128
    else if (t < 33281) { src = a5; i = t - 33280; off = 33280; }   // q_b 1
    else if (t < 98817) { src = a6; i = t - 33281; off = 33296; }   // conv_w 4x128x128
    else if (t < 99713) { src = a7; i = t - 98817; off = 98832; }   // cls_w 128x7
    else                { src = a8; i = t - 99713; off = 99728; }   // cls_b 7
    float v;
    if (*flag) v = ((const float*)src)[i];
    else       v = bf2f1(((const uint16_t*)src)[i]);
    dst[off + i] = v;
}

// ---------------- split-bf16 weight prep, fragment/lane-ordered ----------------
__global__ __launch_bounds__(256) void k_wsplit(const float* __restrict__ stg,
                                                uint16_t* __restrict__ wpkhi, uint16_t* __restrict__ wpklo,
                                                uint16_t* __restrict__ cwkhi, uint16_t* __restrict__ cwklo) {
    int t = blockIdx.x * 256 + threadIdx.x;
    if (t >= 32768 + 65536) return;
    float v; size_t dst; uint16_t *ha, *la;
    if (t < 32768) {
        int k = t >> 7, c = t & 127;
        v = stg[t];
        dst = (size_t)wpack_idx(k, c); ha = wpkhi; la = wpklo;
    } else {
        int u = t - 32768;
        int L = u >> 14, rem = u & 16383;
        int k = rem >> 7, c = rem & 127;
        v = stg[33296 + u];
        dst = (size_t)L * 16384 + wpack_idx(k, c); ha = cwkhi; la = cwklo;
    }
    uint16_t hb = f2bf(v);
    uint16_t lb = f2bf(v - bf2f1(hb));
    ha[dst] = hb; la[dst] = lb;
}

// ---------------- graph prep: atomic-free counting-sort CSR build ----------------

__global__ __launch_bounds__(256) void k_hist(const int* __restrict__ row, int* __restrict__ hist) {
    __shared__ int lh[NBK];
    int b = blockIdx.x, tid = threadIdx.x;
    for (int i = tid; i < NBK; i += 256) lh[i] = 0;
    __syncthreads();
    int e0 = b * CHUNK;
    int lim = N_EDGES - e0; if (lim > CHUNK) lim = CHUNK;
    for (int i = tid; i < lim; i += 256) atomicAdd(&lh[row[e0 + i] >> BSHIFT], 1);
    __syncthreads();
    for (int i = tid; i < NBK; i += 256) hist[(size_t)b * NBK + i] = lh[i];
}

__global__ __launch_bounds__(128) void k_hscan(int* __restrict__ hist, int* __restrict__ totB) {
    __shared__ int s[128];
    int bkt = blockIdx.x, t = threadIdx.x;
    int v = (t < NCH) ? hist[(size_t)t * NBK + bkt] : 0;
    s[t] = v;
    __syncthreads();
    for (int off = 1; off < 128; off <<= 1) {
        int add = (t >= off) ? s[t - off] : 0;
        __syncthreads();
        s[t] += add;
        __syncthreads();
    }
    if (t < NCH) hist[(size_t)t * NBK + bkt] = s[t] - v;   // exclusive within bucket
    if (t == 127) totB[bkt] = s[127];
}

__global__ __launch_bounds__(256) void k_bscan(const int* __restrict__ totB,
                                               int* __restrict__ boffB, int* __restrict__ rp) {
    __shared__ int ps[256];
    int t = threadIdx.x;
    const int STRIP = 7;                     // 256*7 = 1792 >= NBK
    int base = t * STRIP;
    int loc[STRIP]; int sum = 0;
#pragma unroll
    for (int j = 0; j < STRIP; j++) {
        int idx = base + j;
        int v = (idx < NBK) ? totB[idx] : 0;
        loc[j] = sum; sum += v;
    }
    ps[t] = sum;
    __syncthreads();
    int v = ps[t];
    for (int off = 1; off < 256; off <<= 1) {
        int add = (t >= off) ? ps[t - off] : 0;
        __syncthreads();
        ps[t] += add;
        __syncthreads();
    }
    int excl = ps[t] - v;
#pragma unroll
    for (int j = 0; j < STRIP; j++) {
        int idx = base + j;
        if (idx < NBK) boffB[idx] = excl + loc[j];
    }
    if (t == 0) { boffB[NBK] = N_EDGES; rp[N_NODES] = N_EDGES; }
}

__global__ __launch_bounds__(256) void k_sortscat(const int* __restrict__ row, const int* __restrict__ col,
                                                  const int* __restrict__ hist, const int* __restrict__ boffB,
                                                  uint32_t* __restrict__ ebp) {
    __shared__ int dbase[NBK];
    __shared__ int lcnt[NBK];
    int b = blockIdx.x, tid = threadIdx.x;
    for (int i = tid; i < NBK; i += 256) {
        dbase[i] = boffB[i] + hist[(size_t)b * NBK + i];
        lcnt[i] = 0;
    }
    __syncthreads();
    int e0 = b * CHUNK;
    int lim = N_EDGES - e0; if (lim > CHUNK) lim = CHUNK;
    for (int i = tid; i < lim; i += 256) {
        int r = row[e0 + i], c = col[e0 + i];
        int bk = r >> BSHIFT;
        int rank = atomicAdd(&lcnt[bk], 1);
        ebp[dbase[bk] + rank] = ((uint32_t)(r & (BROWS - 1)) << 17) | (uint32_t)c;
    }
}

__global__ __launch_bounds__(256) void k_bfin(const uint32_t* __restrict__ ebp, const int* __restrict__ boffB,
                                              int* __restrict__ rp, float* __restrict__ dis,
                                              int* __restrict__ edc) {
    __shared__ int ldeg[BROWS];
    __shared__ int lcur[BROWS];
    int b = blockIdx.x, tid = threadIdx.x;
    int base = boffB[b];
    int n = boffB[b + 1] - base;
    if (tid < BROWS) ldeg[tid] = 0;
    __syncthreads();
    for (int i = tid; i < n; i += 256) atomicAdd(&ldeg[ebp[base + i] >> 17], 1);
    __syncthreads();
    if (tid == 0) {
        int run = 0;
        for (int r = 0; r < BROWS; r++) { int d = ldeg[r]; lcur[r] = run; run += d; }
    }
    __syncthreads();
    int row0 = b << BSHIFT;
    if (tid < BROWS && row0 + tid < N_NODES) {
        int d = ldeg[tid];
        rp[row0 + tid]  = base + lcur[tid];
        dis[row0 + tid] = rsqrtf((float)(d > 0 ? d : 1));
    }
    __syncthreads();   // rp/dis read lcur before scatter mutates it
    for (int i = tid; i < n; i += 256) {
        uint32_t pk = ebp[base + i];
        int r = pk >> 17;
        int pos = atomicAdd(&lcur[r], 1);
        edc[base + pos] = (int)(pk & 0x1FFFFu);
    }
}

// ---------------- fused SpMM + blend; writes sup as hi/lo bf16 planes ----------------

__global__ __launch_bounds__(256) void k_spmm(const uint32_t* __restrict__ Hq,
                                              const float* __restrict__ ScD,
                                              const float* __restrict__ H0,
                                              const int* __restrict__ rp,
                                              const int* __restrict__ edc,
                                              const float* __restrict__ S,
                                              const float* __restrict__ dis,
                                              uint16_t* __restrict__ SupHi,
                                              uint16_t* __restrict__ SupLo) {
    int wid  = (blockIdx.x * 256 + threadIdx.x) >> 6;
    int lane = threadIdx.x & 63;
    if (wid >= N_NODES) return;

    float s  = S[wid];
    float dr = dis[wid];
    float h0x = H0[(size_t)wid * 128 + lane];
    float h0y = H0[(size_t)wid * 128 + 64 + lane];

    int p0 = rp[wid], p1 = rp[wid + 1];
    float ax = 0.f, ay = 0.f;
    int p = p0;
    for (; p + 8 <= p1; p += 8) {
        int c[8]; uint32_t u[8]; float w[8];
#pragma unroll
        for (int j = 0; j < 8; j++) c[j] = edc[p + j];
#pragma unroll
        for (int j = 0; j < 8; j++) u[j] = Hq[(size_t)c[j] * 64 + lane];
#pragma unroll
        for (int j = 0; j < 8; j++) w[j] = ScD[c[j]];
#pragma unroll
        for (int j = 0; j < 8; j++) {
            ax += w[j] * (float)((int)(u[j] << 16) >> 16);
            ay += w[j] * (float)((int)u[j] >> 16);
        }
    }
    for (; p + 4 <= p1; p += 4) {
        int c[4]; uint32_t u[4]; float w[4];
#pragma unroll
        for (int j = 0; j < 4; j++) c[j] = edc[p + j];
#pragma unroll
        for (int j = 0; j < 4; j++) u[j] = Hq[(size_t)c[j] * 64 + lane];
#pragma unroll
        for (int j = 0; j < 4; j++) w[j] = ScD[c[j]];
#pragma unroll
        for (int j = 0; j < 4; j++) {
            ax += w[j] * (float)((int)(u[j] << 16) >> 16);
            ay += w[j] * (float)((int)u[j] >> 16);
        }
    }
    for (; p < p1; p++) {
        int c = edc[p];
        uint32_t u = Hq[(size_t)c * 64 + lane];
        float w = ScD[c];
        ax += w * (float)((int)(u << 16) >> 16);
        ay += w * (float)((int)u >> 16);
    }
    float f = (1.f - s) * dr;
    float ox = f * ax + s * h0x;
    float oy = f * ay + s * h0y;
    uint16_t hx = f2bf(ox), hy = f2bf(oy);
    uint16_t lx = f2bf(ox - bf2f1(hx)), ly = f2bf(oy - bf2f1(hy));
    SupHi[(size_t)wid * 128 + lane]      = hx;
    SupHi[(size_t)wid * 128 + 64 + lane] = hy;
    SupLo[(size_t)wid * 128 + lane]      = lx;
    SupLo[(size_t)wid * 128 + 64 + lane] = ly;
}

// ---------------- MFMA GEMM: W chunk in LDS (frag-packed), A in regs, LN/gate/quant ----
// Block = 128 rows, 4 waves; wave wv owns rows wb=wv*32 + {li, li+16} (two acc sets).
// Per 128-K chunk: stage W hi(+lo) 32(64)KB once -> barrier -> barrier-free MFMA loop.
// B-frag = one contiguous ds_read_b128; A-frags preloaded to regs under the staging.
// C layout: col=lane&15, row=(lane>>4)*4+reg (per 16-row set).
// Split products: C = Ah*Wh [+ Al*Wh if A fp32] [+ Ah*Wl if W fp32].
// MODE0: A=x global (fp32/bf16 by WF). MODE1: A = SupHi/SupLo bf16 planes.

template <int KD, int MODE, int WH, int WQ, int WF>
__global__ __launch_bounds__(256, 2) void k_gemm(
    const void* __restrict__ Ax,
    const uint16_t* __restrict__ Ahi, const uint16_t* __restrict__ Alo,
    const uint16_t* __restrict__ Wh, const uint16_t* __restrict__ Wl,
    const float* __restrict__ bias, const float* __restrict__ gamma,
    const float* __restrict__ beta, const float* __restrict__ qw,
    const float* __restrict__ qb, float theta, const int* __restrict__ flag,
    const float* __restrict__ dis,
    float* __restrict__ Hout, uint32_t* __restrict__ Hq,
    float* __restrict__ Sc, float* __restrict__ S)
{
    if (*flag != WF) return;             // guarded dual-launch fallback
    constexpr int F32A = (MODE == 0) ? WF : 1;   // A has a lo plane
    constexpr int NKB = KD / 128;

    __shared__ __align__(16) uint16_t sWh[16384];   // 32 KiB
    __shared__ __align__(16) uint16_t sWl[16384];   // 32 KiB

    const int tid  = threadIdx.x;
    const int lane = tid & 63;
    const int wv   = tid >> 6;
    const int li   = lane & 15;
    const int lg   = lane >> 4;
    const size_t row0 = (size_t)blockIdx.x * 128;
    const int wb = wv * 32;
    size_t ar0 = row0 + wb + li;      if (ar0 >= N_NODES) ar0 = N_NODES - 1;
    size_t ar1 = row0 + wb + 16 + li; if (ar1 >= N_NODES) ar1 = N_NODES - 1;

    f32x4 acc0[8], acc1[8];
#pragma unroll
    for (int ct = 0; ct < 8; ct++) {
        acc0[ct] = (f32x4){0.f, 0.f, 0.f, 0.f};
        acc1[ct] = (f32x4){0.f, 0.f, 0.f, 0.f};
    }

    for (int kb = 0; kb < NKB; kb++) {
        if (kb) __syncthreads();
        // stage W chunk (linear copy; packed order == LDS read order)
        const uint16_t* gh = Wh + kb * 16384;
#pragma unroll
        for (int it = 0; it < 8; it++) {
            int t = tid + it * 256;
            *(uint4*)(sWh + t * 8) = *(const uint4*)(gh + t * 8);
        }
        if constexpr (WF) {
            const uint16_t* gl = Wl + kb * 16384;
#pragma unroll
            for (int it = 0; it < 8; it++) {
                int t = tid + it * 256;
                *(uint4*)(sWl + t * 8) = *(const uint4*)(gl + t * 8);
            }
        }
        // preload this chunk's A fragments (latency hidden under staging + barrier)
        bf16x8 a0h[4], a1h[4], a0l[4], a1l[4];
#pragma unroll
        for (int s = 0; s < 4; s++) {
            const int koff = kb * 128 + s * 32 + lg * 8;
            if constexpr (MODE == 1) {
                a0h[s] = *(const bf16x8*)(Ahi + ar0 * KD + koff);
                a0l[s] = *(const bf16x8*)(Alo + ar0 * KD + koff);
                a1h[s] = *(const bf16x8*)(Ahi + ar1 * KD + koff);
                a1l[s] = *(const bf16x8*)(Alo + ar1 * KD + koff);
            } else if constexpr (WF) {
                const float* p0 = (const float*)Ax + ar0 * KD + koff;
                const float* p1 = (const float*)Ax + ar1 * KD + koff;
                float4 u0 = *(const float4*)p0, u1 = *(const float4*)(p0 + 4);
                float4 v0 = *(const float4*)p1, v1 = *(const float4*)(p1 + 4);
                float f0[8] = {u0.x, u0.y, u0.z, u0.w, u1.x, u1.y, u1.z, u1.w};
                float f1[8] = {v0.x, v0.y, v0.z, v0.w, v1.x, v1.y, v1.z, v1.w};
#pragma unroll
                for (int j = 0; j < 8; j++) {
                    uint16_t hb0 = f2bf(f0[j]);
                    a0h[s][j] = (short)hb0;
                    a0l[s][j] = (short)f2bf(f0[j] - bf2f1(hb0));
                    uint16_t hb1 = f2bf(f1[j]);
                    a1h[s][j] = (short)hb1;
                    a1l[s][j] = (short)f2bf(f1[j] - bf2f1(hb1));
                }
            } else {
                a0h[s] = *(const bf16x8*)((const uint16_t*)Ax + ar0 * KD + koff);
                a1h[s] = *(const bf16x8*)((const uint16_t*)Ax + ar1 * KD + koff);
            }
        }
        __syncthreads();
        // barrier-free MFMA loop: all operands LDS/regs
#pragma unroll
        for (int s = 0; s < 4; s++) {
#pragma unroll
            for (int ct = 0; ct < 8; ct++) {
                const int wo = ((s * 8 + ct) * 64 + lane) * 8;
                bf16x8 bh = *(const bf16x8*)(sWh + wo);
                acc0[ct] = __builtin_amdgcn_mfma_f32_16x16x32_bf16(a0h[s], bh, acc0[ct], 0, 0, 0);
                acc1[ct] = __builtin_amdgcn_mfma_f32_16x16x32_bf16(a1h[s], bh, acc1[ct], 0, 0, 0);
                if constexpr (F32A) {
                    acc0[ct] = __builtin_amdgcn_mfma_f32_16x16x32_bf16(a0l[s], bh, acc0[ct], 0, 0, 0);
                    acc1[ct] = __builtin_amdgcn_mfma_f32_16x16x32_bf16(a1l[s], bh, acc1[ct], 0, 0, 0);
                }
                if constexpr (WF) {
                    bf16x8 bl = *(const bf16x8*)(sWl + wo);
                    acc0[ct] = __builtin_amdgcn_mfma_f32_16x16x32_bf16(a0h[s], bl, acc0[ct], 0, 0, 0);
                    acc1[ct] = __builtin_amdgcn_mfma_f32_16x16x32_bf16(a1h[s], bl, acc1[ct], 0, 0, 0);
                }
            }
        }
    }

    // ---- epilogue: per (lane, reg, set) one row, cols {ct*16+li} ----
    float gm[8], bt_[8], qv[8], bi[8];
#pragma unroll
    for (int ct = 0; ct < 8; ct++) {
        int c = ct * 16 + li;
        gm[ct] = gamma[c]; bt_[ct] = beta[c]; qv[ct] = qw[c];
        bi[ct] = (MODE == 0) ? bias[c] : 0.f;
    }
    const float qbv = qb[0];
    const float om  = 1.f - theta;

    auto epi = [&](f32x4 (&acc)[8], int ssoff) {
#pragma unroll
        for (int r = 0; r < 4; r++) {
            int rowl  = wb + ssoff + lg * 4 + r;
            size_t rg = row0 + rowl;
            size_t rc = (rg < N_NODES) ? rg : (N_NODES - 1);
            float v[8];
            if (MODE == 0) {
#pragma unroll
                for (int ct = 0; ct < 8; ct++) v[ct] = acc[ct][r] + bi[ct];
            } else {
#pragma unroll
                for (int ct = 0; ct < 8; ct++) {
                    int c = ct * 16 + li;
                    float sv = bf2f1(Ahi[rc * KD + c]) + bf2f1(Alo[rc * KD + c]);
                    float o  = theta * acc[ct][r] + om * sv;
                    v[ct] = o > 0.f ? o : 0.f;
                }
            }
            float sum = 0.f, sq = 0.f;
#pragma unroll
            for (int ct = 0; ct < 8; ct++) { sum += v[ct]; sq += v[ct] * v[ct]; }
            sum += __shfl_xor(sum, 1); sum += __shfl_xor(sum, 2);
            sum += __shfl_xor(sum, 4); sum += __shfl_xor(sum, 8);
            sq  += __shfl_xor(sq, 1);  sq  += __shfl_xor(sq, 2);
            sq  += __shfl_xor(sq, 4);  sq  += __shfl_xor(sq, 8);
            float mu  = sum * (1.f / 128.f);
            float var = fmaxf(sq * (1.f / 128.f) - mu * mu, 0.f);
            float rs  = rsqrtf(var + LN_EPS);
            float y[8];
#pragma unroll
            for (int ct = 0; ct < 8; ct++) y[ct] = gm[ct] * (v[ct] - mu) * rs + bt_[ct];

            if (WQ) {
                float zd = 0.f, am = 0.f;
#pragma unroll
                for (int ct = 0; ct < 8; ct++) { zd += y[ct] * qv[ct]; am = fmaxf(am, fabsf(y[ct])); }
                zd += __shfl_xor(zd, 1); zd += __shfl_xor(zd, 2);
                zd += __shfl_xor(zd, 4); zd += __shfl_xor(zd, 8);
                am = fmaxf(am, __shfl_xor(am, 1)); am = fmaxf(am, __shfl_xor(am, 2));
                am = fmaxf(am, __shfl_xor(am, 4)); am = fmaxf(am, __shfl_xor(am, 8));
                float amc  = fmaxf(am, 1e-20f);
                float qinv = 32767.f / amc;
                if (rg < N_NODES) {
                    uint32_t* mq = Hq + rg * 64;
#pragma unroll
                    for (int ct = 0; ct < 4; ct++)
                        mq[ct * 16 + li] = packq(y[ct], y[ct + 4], qinv);  // pair (c, c+64)
                    if (li == 0) {
                        Sc[rg] = amc * (1.f / 32767.f) * dis[rg];
                        S[rg]  = 1.f / (1.f + __expf(-(zd + qbv - 1.f)));
                    }
                }
            }
            if (WH && rg < N_NODES) {
                float* dst = Hout + rg * 128;
#pragma unroll
                for (int ct = 0; ct < 8; ct++) dst[ct * 16 + li] = y[ct];
            }
        }
    };
    epi(acc0, 0);
    epi(acc1, 16);
}

// ---------------- classifier (fp32 in, dtype-flag out) ----------------

__global__ __launch_bounds__(256) void k_cls(const float* __restrict__ H,
                                             const float* __restrict__ Wc,
                                             const float* __restrict__ bc,
                                             const int* __restrict__ flag,
                                             void* __restrict__ out) {
    __shared__ float wS[128][8];
    int tid = threadIdx.x;
    for (int idx = tid; idx < 128 * 7; idx += 256) wS[idx / 7][idx % 7] = Wc[idx];
    __syncthreads();
    int isf32 = *flag;
    int gid = blockIdx.x * 256 + tid;
    int n = gid >> 3, j = gid & 7;
    if (n >= N_NODES || j >= OUT_DIM) return;
    const float4* hr = (const float4*)(H + (size_t)n * 128);
    float acc = bc[j];
#pragma unroll
    for (int k4 = 0; k4 < 32; k4++) {
        float4 h4 = hr[k4];
        acc += h4.x * wS[4 * k4][j]     + h4.y * wS[4 * k4 + 1][j]
             + h4.z * wS[4 * k4 + 2][j] + h4.w * wS[4 * k4 + 3][j];
    }
    size_t oi = (size_t)n * OUT_DIM + j;
    if (isf32) ((float*)out)[oi] = acc;
    else       ((uint16_t*)out)[oi] = f2bf(acc);
}

// ---------------- launch ----------------

extern "C" void kernel_launch(void* const* d_in, const int* in_sizes, int n_in,
                              void* d_out, int out_size, void* d_ws, size_t ws_size,
                              hipStream_t stream) {
    const void* x_raw = d_in[0];
    const int*  ei    = (const int*)d_in[1];
    const int* row = ei;
    const int* col = ei + N_EDGES;

    char* ws = (char*)d_ws;
    size_t off = 0;
    auto alloc = [&](size_t b) { void* p = ws + off; off = (off + b + 255) & ~(size_t)255; return p; };
    int*      flag = (int*)alloc(4);
    float*    stgf = (float*)alloc((size_t)99744 * 4);
    int*      rp   = (int*)alloc(((size_t)N_NODES + 1) * 4);
    float*    dis  = (float*)alloc((size_t)N_NODES * 4);
    int*      hist = (int*)alloc((size_t)NCH * NBK * 4);
    int*      totB = (int*)alloc((size_t)NBK * 4);
    int*      boffB= (int*)alloc(((size_t)NBK + 1) * 4);
    int*      edc  = (int*)alloc((size_t)N_EDGES * 4);             // CSR cols (4B)
    float*    h0   = (float*)alloc((size_t)N_NODES * HID * 4);     // also final h (WH of last GEMM)
    uint16_t* suphi= (uint16_t*)alloc((size_t)N_NODES * HID * 2);  // support hi plane
    uint16_t* suplo= (uint16_t*)alloc((size_t)N_NODES * HID * 2);  // support lo plane
    uint32_t* hq   = (uint32_t*)alloc((size_t)N_NODES * 64 * 4);   // int16 mirror
    float*    Scq  = (float*)alloc((size_t)N_NODES * 4);           // quant scale * dis
    float*    Sg   = (float*)alloc((size_t)N_NODES * 4);           // gate sigmoid
    uint16_t* wpkhi = (uint16_t*)alloc((size_t)32768 * 2);         // W_proj packed hi
    uint16_t* wpklo = (uint16_t*)alloc((size_t)32768 * 2);
    uint16_t* cwkhi = (uint16_t*)alloc((size_t)65536 * 2);         // conv_w packed hi (4 layers)
    uint16_t* cwklo = (uint16_t*)alloc((size_t)65536 * 2);
    uint32_t* ebp  = (uint32_t*)h0;   // bucket-sorted packed edges (6.4MB) alias h0

    const float* bp  = stgf + 32768;
    const float* gm  = stgf + 32896;
    const float* bt  = stgf + 33024;
    const float* qw  = stgf + 33152;
    const float* qb  = stgf + 33280;
    const float* clw = stgf + 98832;
    const float* clb = stgf + 99728;

    // host-side dtype detection from byte sizes; -1 = unknown -> guarded dual launch
    int hostflag = -1;
    if (in_sizes && n_in >= 3) {
        if      (in_sizes[2] == 32768 * 4) hostflag = 1;
        else if (in_sizes[2] == 32768 * 2) hostflag = 0;
        else if (in_sizes[0] == N_NODES * IN_DIM * 4) hostflag = 1;
        else if (in_sizes[0] == N_NODES * IN_DIM * 2) hostflag = 0;
    }
    if (hostflag >= 0) k_setflag<<<1, 64, 0, stream>>>(flag, hostflag);
    else               k_detect<<<1, 64, 0, stream>>>((const uint32_t*)d_in[2], flag);

    k_cvt<<<(99720 + 255) / 256, 256, 0, stream>>>(d_in[2], d_in[3], d_in[4], d_in[5], d_in[6],
                                                   d_in[7], d_in[8], d_in[9], d_in[10], stgf, flag);
    k_wsplit<<<(98304 + 255) / 256, 256, 0, stream>>>(stgf, wpkhi, wpklo, cwkhi, cwklo);

    k_hist<<<NCH, 256, 0, stream>>>(row, hist);
    k_hscan<<<NBK, 128, 0, stream>>>(hist, totB);
    k_bscan<<<1, 256, 0, stream>>>(totB, boffB, rp);
    k_sortscat<<<NCH, 256, 0, stream>>>(row, col, hist, boffB, ebp);
    k_bfin<<<NBK, 256, 0, stream>>>(ebp, boffB, rp, dis, edc);

    const int gg = (N_NODES + 127) / 128;   // 782
    if (hostflag != 0)
        k_gemm<IN_DIM, 0, 1, 1, 1><<<gg, 256, 0, stream>>>(
            x_raw, nullptr, nullptr, wpkhi, wpklo, bp, gm, bt, qw, qb, 0.f, flag, dis,
            h0, hq, Scq, Sg);
    if (hostflag != 1)
        k_gemm<IN_DIM, 0, 1, 1, 0><<<gg, 256, 0, stream>>>(
            x_raw, nullptr, nullptr, wpkhi, wpklo, bp, gm, bt, qw, qb, 0.f, flag, dis,
            h0, hq, Scq, Sg);

    for (int i = 0; i < N_LAYERS; i++) {
        k_spmm<<<(N_NODES + 3) / 4, 256, 0, stream>>>(hq, Scq, h0, rp, edc, Sg, dis, suphi, suplo);
        float theta = 0.5f / (float)(i + 1);
        const uint16_t* whi = cwkhi + (size_t)i * 16384;
        const uint16_t* wlo = cwklo + (size_t)i * 16384;
        const int wh = (i == N_LAYERS - 1) ? 1 : 0;
        if (wh) {
            if (hostflag != 0)
                k_gemm<HID, 1, 1, 0, 1><<<gg, 256, 0, stream>>>(
                    nullptr, suphi, suplo, whi, wlo, nullptr, gm, bt, qw, qb, theta, flag, dis,
                    h0, hq, Scq, Sg);
            if (hostflag != 1)
                k_gemm<HID, 1, 1, 0, 0><<<gg, 256, 0, stream>>>(
                    nullptr, suphi, suplo, whi, wlo, nullptr, gm, bt, qw, qb, theta, flag, dis,
                    h0, hq, Scq, Sg);
        } else {
            if (hostflag != 0)
                k_gemm<HID, 1, 0, 1, 1><<<gg, 256, 0, stream>>>(
                    nullptr, suphi, suplo, whi, wlo, nullptr, gm, bt, qw, qb, theta, flag, dis,
                    h0, hq, Scq, Sg);
            if (hostflag != 1)
                k_gemm<HID, 1, 0, 1, 0><<<gg, 256, 0, stream>>>(
                    nullptr, suphi, suplo, whi, wlo, nullptr, gm, bt, qw, qb, theta, flag, dis,
                    h0, hq, Scq, Sg);
        }
    }
    k_cls<<<((size_t)N_NODES * 8 + 255) / 256, 256, 0, stream>>>(h0, clw, clb, flag, d_out);
}